// Round 16
// baseline (334.554 us; speedup 1.0000x reference)
//
#include <hip/hip_runtime.h>

// HierarchicalAttentionModule on MI355X (gfx950).
// B=8, C=256, H=W=48, N=2304. All inputs fp32, output fp32.
// Round 16: round-13 exact (251.7us best; r15's V-pad made conflicts 3x
// WORSE and is reverted) + ONE change: flash __launch_bounds__(256,3).
// Register arithmetic: r13 flash = ~100 arch VGPR + 64 AGPR = 164 unified;
// 3 waves/SIMD needs 492 <= 512 -> fits WITHOUT a squeeze (unlike r10's
// flash which carried +64 staging regs and spilled at this bound).
// LDS 3 x 37.9KB = 114KB <= 160KB. Expect 3 blocks/CU.

typedef unsigned short u16;
typedef unsigned int u32;
typedef __attribute__((ext_vector_type(8))) u16 u16x8;
typedef __attribute__((ext_vector_type(4))) float f32x4;
typedef __attribute__((ext_vector_type(4))) float f4;
typedef __attribute__((ext_vector_type(8))) __bf16 bf16x8;

#define DEVINL __device__ __forceinline__

constexpr int C = 256;
constexpr int N = 2304;
constexpr int HW = 48;
constexpr int BSTRIDE = C * N;   // elements per batch
constexpr int BN = 8 * N;        // 18432
constexpr int XPAD_ROWS = 54 * 54;  // 2916 padded positions (xpad)
constexpr int SPAD_ROWS = 54 * 48;  // 2592 padded positions (sb_pad)

DEVINL u16 f2bf(float f) {
  u32 u = __builtin_bit_cast(u32, f);
  u += 0x7fffu + ((u >> 16) & 1u);
  return (u16)(u >> 16);
}
DEVINL float bf2f(u16 h) {
  u32 u = ((u32)h) << 16;
  return __builtin_bit_cast(float, u);
}
DEVINL u16x8 ld8(const u16* p) { return *reinterpret_cast<const u16x8*>(p); }
DEVINL void st8(u16* p, u16x8 v) { *reinterpret_cast<u16x8*>(p) = v; }
DEVINL f32x4 mfma16(u16x8 a, u16x8 b, f32x4 c) {
  return __builtin_amdgcn_mfma_f32_16x16x32_bf16(
      __builtin_bit_cast(bf16x8, a), __builtin_bit_cast(bf16x8, b), c, 0, 0, 0);
}
DEVINL void gl16(const void* g, void* l) {
  __builtin_amdgcn_global_load_lds(
      (const __attribute__((address_space(1))) u32*)g,
      (__attribute__((address_space(3))) u32*)l, 16, 0, 0);
}

// ---------------------------------------------------------------------------
// prep: blocks [0,704) zero xpad+sbpad; [704,960) weight casts/repacks;
//       [960,1984) spatial mean (2 rows per block).
__global__ __launch_bounds__(256) void prep_kernel(
    const float* __restrict__ x,
    const float* __restrict__ wq, const float* __restrict__ wk,
    const float* __restrict__ wv, const float* __restrict__ wa,
    const float* __restrict__ s1w, const float* __restrict__ s2w,
    const float* __restrict__ lw,
    u16* __restrict__ xpad, u16* __restrict__ sbpad,
    u16* __restrict__ wqh, u16* __restrict__ wkh,
    u16* __restrict__ wvb, u16* __restrict__ wab,
    u16* __restrict__ s1rep, u16* __restrict__ s2rep, u16* __restrict__ lwrep,
    float* __restrict__ mb) {
  const int blk = blockIdx.x;
  const int t = threadIdx.x;
  if (blk < 704) {
    const long CX = (long)8 * XPAD_ROWS * C / 8;
    const long CS = (long)8 * SPAD_ROWS * C / 8;
    u16x8 z = {0, 0, 0, 0, 0, 0, 0, 0};
    for (long k = (long)blk * 256 + t; k < CX + CS; k += 704L * 256) {
      if (k < CX) st8(xpad + k * 8, z);
      else st8(sbpad + (k - CX) * 8, z);
    }
  } else if (blk < 960) {
    int base = (blk - 704) * 256 + t;  // [0, 65536)
    wqh[base] = f2bf(wq[base]);
    wkh[base] = f2bf(wk[base]);
    wvb[base] = f2bf(wv[base]);
    wab[base] = f2bf(wa[base]);
    size_t b7 = (size_t)base * 7, b9 = (size_t)base * 9;
#pragma unroll
    for (int tp = 0; tp < 7; ++tp) s1rep[tp * 65536 + base] = f2bf(s1w[b7 + tp]);
#pragma unroll
    for (int tp = 0; tp < 7; ++tp) s2rep[tp * 65536 + base] = f2bf(s2w[b7 + tp]);
#pragma unroll
    for (int tp = 0; tp < 9; ++tp) lwrep[tp * 65536 + base] = f2bf(lw[b9 + tp]);
  } else {
    __shared__ float ws4[4];
    int r0 = (blk - 960) * 2;
#pragma unroll
    for (int rr = 0; rr < 2; ++rr) {
      const float* p = x + (size_t)(r0 + rr) * N;
      float s = 0.f;
      for (int i = t; i < N; i += 256) s += p[i];
#pragma unroll
      for (int off = 32; off >= 1; off >>= 1) s += __shfl_xor(s, off);
      if ((t & 63) == 0) ws4[t >> 6] = s;
      __syncthreads();
      if (t == 0) mb[r0 + rr] = (ws4[0] + ws4[1] + ws4[2] + ws4[3]) * (1.f / N);
      __syncthreads();
    }
  }
}

// ---------------------------------------------------------------------------
// x [B][C][N] fp32 -> xT bf16 [B][N][C]  +  xpad_hi [B][2916][C]
__global__ __launch_bounds__(256) void split_x_kernel(
    const float* __restrict__ x, u16* __restrict__ xhi,
    u16* __restrict__ xpad) {
  const int b = blockIdx.z;
  const int p0 = blockIdx.x * 64;
  const int c0 = blockIdx.y * 64;
  const int tid = threadIdx.x;
  __shared__ float tile[64][65];
#pragma unroll
  for (int it = 0; it < 4; ++it) {
    int idx = it * 256 + tid;
    int cr = idx >> 4, pc = (idx & 15) * 4;
    f4 v = *reinterpret_cast<const f4*>(&x[((size_t)b * C + c0 + cr) * N + p0 + pc]);
    tile[cr][pc] = v[0];
    tile[cr][pc + 1] = v[1];
    tile[cr][pc + 2] = v[2];
    tile[cr][pc + 3] = v[3];
  }
  __syncthreads();
#pragma unroll
  for (int it = 0; it < 2; ++it) {
    int idx = it * 256 + tid;
    int pr = idx >> 3, cg = (idx & 7) * 8;
    u16x8 h8;
#pragma unroll
    for (int j = 0; j < 8; ++j) h8[j] = f2bf(tile[cg + j][pr]);
    int p = p0 + pr;
    size_t o = ((size_t)b * N + p) * C + c0 + cg;
    st8(xhi + o, h8);
    int hh = p / HW, ww = p - hh * HW;
    size_t op = ((size_t)b * XPAD_ROWS + (size_t)(hh + 3) * 54 + ww + 3) * C + c0 + cg;
    st8(xpad + op, h8);
  }
}

__global__ __launch_bounds__(256) void global_kernel(
    const float* __restrict__ m, const float* __restrict__ g1w,
    const float* __restrict__ g1b, const float* __restrict__ g2w,
    const float* __restrict__ g2b, float* __restrict__ gatt) {
  int b = blockIdx.x, t = threadIdx.x;
  __shared__ float ms[256], hid[32];
  ms[t] = m[b * 256 + t];
  __syncthreads();
  if (t < 32) {
    float s = g1b[t];
    const float* wr = g1w + t * 256;
    for (int c2 = 0; c2 < 256; ++c2) s += ms[c2] * wr[c2];
    hid[t] = fmaxf(s, 0.f);
  }
  __syncthreads();
  float s = g2b[t];
#pragma unroll
  for (int j = 0; j < 32; ++j) s += hid[j] * g2w[t * 32 + j];
  gatt[b * 256 + t] = 1.f / (1.f + __expf(-s));
}

// ---------------------------------------------------------------------------
// Descriptor-driven fused GEMM (round-13 single-buffer m97 structure).
struct OpDesc {
  const u16* Xh;
  const u16* W;
  const float* bias;  // nullptr -> raw partial (no bias/act)
  u16* o0;
  int tk;      // 0 none, 1 = 1x7, 2 = 7x1, 3 = 3x3
  int act;     // 0 none, 1 relu, 2 sigmoid
  int outn;    // 0: out[pos][o], 1: out[o][pos]
  int opad;    // output to sb_pad geometry
  int ips;     // input rows per batch
  int idy;     // row delta for dy=+1
  int iox;     // column origin
  int s0, s1;  // step range over flattened (tap, ks)
};
struct OpPack {
  OpDesc d[6];
  int chunk;  // nwg/8 for XCD swizzle
  int ny;
};

__global__ __launch_bounds__(256, 3) void fused_gemm_kernel(OpPack pk) {
  const int swz = (blockIdx.x & 7) * pk.chunk + (blockIdx.x >> 3);
  const int xt = swz % 18;
  const int rest = swz / 18;
  const int y = rest % pk.ny;
  const int z = rest / pk.ny;
  const OpDesc dd = pk.d[y >> 1];
  const int mbase = xt * 128;
  const int nbase = (y & 1) * 128;
  const int tid = threadIdx.x;
  const int lane = tid & 63;
  const int wid = tid >> 6;
  const int wm = wid >> 1, wn = wid & 1;
  const int tk = dd.tk;

  __shared__ __align__(16) u16 ldsX[128 * 64];
  __shared__ __align__(16) u16 ldsW[128 * 64];

  f32x4 acc[4][4];
#pragma unroll
  for (int m = 0; m < 4; ++m)
#pragma unroll
    for (int n = 0; n < 4; ++n) acc[m][n] = f32x4{0.f, 0.f, 0.f, 0.f};

  size_t xrow[4], wrow[4];
#pragma unroll
  for (int it = 0; it < 4; ++it) {
    int idx = it * 256 + tid;
    int rr = idx >> 3, ss = idx & 7;
    int perm = ss ^ (rr & 7);
    int p = mbase + rr;
    if (tk == 0) {
      xrow[it] = ((size_t)z * N + p) * 512 + (size_t)perm * 16;
    } else {
      int hh = p / HW, ww = p - hh * HW;
      xrow[it] = ((size_t)z * dd.ips + (size_t)(hh + 3) * dd.idy + ww + dd.iox) * 512 +
                 (size_t)perm * 16;
    }
    wrow[it] = ((size_t)(nbase + rr)) * 512 + (size_t)perm * 16;
  }
  int aoff[2][4], boff[2][4];
#pragma unroll
  for (int kk = 0; kk < 2; ++kk) {
    int seg = kk * 4 + (lane >> 4);
#pragma unroll
    for (int m = 0; m < 4; ++m) {
      int ra = wm * 64 + m * 16 + (lane & 15);
      aoff[kk][m] = ra * 64 + ((seg ^ (ra & 7)) << 3);
      int rb = wn * 64 + m * 16 + (lane & 15);
      boff[kk][m] = rb * 64 + ((seg ^ (rb & 7)) << 3);
    }
  }

  auto stage = [&](int tap, int ks) {
    const char* xs = (const char*)dd.Xh;
    const char* wsrc = (const char*)dd.W + (size_t)tap * 131072;
    int tsh = 0;
    if (tk == 1) tsh = tap - 3;
    else if (tk == 2) tsh = (tap - 3) * dd.idy;
    else if (tk == 3) tsh = (tap / 3 - 1) * dd.idy + (tap % 3 - 1);
    const long xadd = (long)tsh * 512 + ks * 128;
    const long wadd = ks * 128;
#pragma unroll
    for (int it = 0; it < 4; ++it) {
      gl16(xs + xrow[it] + xadd, &ldsX[(it * 4 + wid) * 512]);
      gl16(wsrc + wrow[it] + wadd, &ldsW[(it * 4 + wid) * 512]);
    }
  };

  int t0 = dd.s0;
  int cks = t0 & 3;
  int ctap = t0 >> 2;
  stage(ctap, cks);

#pragma unroll 1
  for (int t = dd.s0; t < dd.s1; ++t) {
    __syncthreads();  // staging drained & visible
    const u16* Alds = dd.outn ? ldsW : ldsX;
    const u16* Blds = dd.outn ? ldsX : ldsW;
#pragma unroll
    for (int kk = 0; kk < 2; ++kk) {
      u16x8 af[4], bfr[4];
#pragma unroll
      for (int m = 0; m < 4; ++m) af[m] = ld8(&Alds[aoff[kk][m]]);
#pragma unroll
      for (int n = 0; n < 4; ++n) bfr[n] = ld8(&Blds[boff[kk][n]]);
      __builtin_amdgcn_s_setprio(1);
#pragma unroll
      for (int m = 0; m < 4; ++m)
#pragma unroll
        for (int n = 0; n < 4; ++n)
          acc[m][n] = mfma16(af[m], bfr[n], acc[m][n]);
      __builtin_amdgcn_s_setprio(0);
    }
    __syncthreads();  // all LDS reads done before next stage overwrites
    if (t + 1 < dd.s1) {
      if (++cks == 4) { cks = 0; ++ctap; }
      stage(ctap, cks);
    }
  }

  const int r4 = (lane >> 4) * 4, cl = lane & 15;
  const size_t xb = (size_t)z * BSTRIDE;
#pragma unroll
  for (int m = 0; m < 4; ++m) {
#pragma unroll
    for (int n = 0; n < 4; ++n) {
#pragma unroll
      for (int i = 0; i < 4; ++i) {
        int lrow = wm * 64 + m * 16 + r4 + i;
        int lcol = wn * 64 + n * 16 + cl;
        int o = dd.outn ? (nbase + lrow) : (nbase + lcol);
        int pos = dd.outn ? (mbase + lcol) : (mbase + lrow);
        float v = acc[m][n][i];
        if (dd.bias) {
          v += dd.bias[o];
          if (dd.act == 1) v = fmaxf(v, 0.f);
          else if (dd.act == 2) v = 1.f / (1.f + __expf(-v));
        }
        size_t oi;
        if (dd.opad) {
          int hh = pos / HW, ww = pos - hh * HW;
          oi = ((size_t)z * SPAD_ROWS + (size_t)(hh + 3) * 48 + ww) * C + o;
        } else {
          oi = xb + (dd.outn ? ((size_t)o * N + pos) : ((size_t)pos * C + o));
        }
        dd.o0[oi] = f2bf(v);
      }
    }
  }
}

// ---------------------------------------------------------------------------
// Flash attention, split-K=4 (round-13 structure exactly). 1-term QK; K/V
// register prefetch; ones-MFMA row-sum; defer-max. (256,3): 164 unified
// regs/wave x 3 = 492 <= 512 -> 3 blocks/CU without spilling.
__global__ __launch_bounds__(256, 3) void flash_kernel(
    const u16* __restrict__ Qhi, const u16* __restrict__ Khi,
    const u16* __restrict__ Vb, u16* __restrict__ P0, u16* __restrict__ P1,
    u16* __restrict__ P2, u16* __restrict__ P3, float* __restrict__ ML) {
  const int b = blockIdx.y;
  const int split = blockIdx.z;
  const int q0 = blockIdx.x * 64;
  const int tid = threadIdx.x;
  const int lane = tid & 63;
  const int wid = tid >> 6;
  const int qbase = q0 + wid * 16;
  const int bb = b * N;
  const u16* Vp = Vb + (size_t)b * BSTRIDE;

  __shared__ __align__(16) u16 lds_kh[32 * 256];
  __shared__ __align__(16) u16 lds_v[256 * 32];
  __shared__ __align__(16) u16 p_lds[4][16 * 40];

  u16x8 qfh[8];
  {
    size_t base = ((size_t)(bb + qbase + (lane & 15))) * C + (lane >> 4) * 8;
#pragma unroll
    for (int kc = 0; kc < 8; ++kc) qfh[kc] = ld8(Qhi + base + kc * 32);
  }
  const u16x8 ones = {0x3F80, 0x3F80, 0x3F80, 0x3F80,
                      0x3F80, 0x3F80, 0x3F80, 0x3F80};  // bf16 1.0

  f32x4 o_acc[16];
#pragma unroll
  for (int j = 0; j < 16; ++j) o_acc[j] = f32x4{0.f, 0.f, 0.f, 0.f};
  float m_r[4] = {-1e30f, -1e30f, -1e30f, -1e30f};
  f32x4 l_acc = {0.f, 0.f, 0.f, 0.f};

  u16x8 skh[4], sv[4];
  const int kt0 = split * 18;
  auto issue = [&](int kt) {
    const int k0 = kt * 32;
#pragma unroll
    for (int it = 0; it < 4; ++it) {
      int idx = it * 256 + tid;
      int r = idx >> 5, s = idx & 31;
      skh[it] = ld8(Khi + (size_t)(bb + k0 + r) * C + s * 8);
      int c2 = idx >> 2, s2 = idx & 3;
      sv[it] = ld8(Vp + (size_t)c2 * N + k0 + s2 * 8);
    }
  };
  issue(kt0);

#pragma unroll 1
  for (int t2 = 0; t2 < 18; ++t2) {
    __syncthreads();
#pragma unroll
    for (int it = 0; it < 4; ++it) {
      int idx = it * 256 + tid;
      int r = idx >> 5, s = idx & 31;
      st8(&lds_kh[r * 256 + ((s ^ (r & 7)) << 3)], skh[it]);
      int c2 = idx >> 2, s2 = idx & 3;
      st8(&lds_v[c2 * 32 + ((s2 ^ ((c2 >> 1) & 3)) << 3)], sv[it]);
    }
    __syncthreads();
    if (t2 < 17) issue(kt0 + t2 + 1);

    // 1-term QK^T
    f32x4 sa0 = {0.f, 0.f, 0.f, 0.f}, sa1 = {0.f, 0.f, 0.f, 0.f};
    __builtin_amdgcn_s_setprio(1);
#pragma unroll
    for (int kc = 0; kc < 8; ++kc) {
      int seg = kc * 4 + (lane >> 4);
      int r0 = lane & 15, r1 = 16 + (lane & 15);
      u16x8 b0 = ld8(&lds_kh[r0 * 256 + ((seg ^ (r0 & 7)) << 3)]);
      u16x8 b1 = ld8(&lds_kh[r1 * 256 + ((seg ^ (r1 & 7)) << 3)]);
      sa0 = mfma16(qfh[kc], b0, sa0);
      sa1 = mfma16(qfh[kc], b1, sa1);
    }
    __builtin_amdgcn_s_setprio(0);

    // online softmax with defer-max (THR=8); row max via 4 shuffles
    float tm[4];
#pragma unroll
    for (int i = 0; i < 4; ++i) {
      float v = fmaxf(sa0[i], sa1[i]);
      v = fmaxf(v, __shfl_xor(v, 1));
      v = fmaxf(v, __shfl_xor(v, 2));
      v = fmaxf(v, __shfl_xor(v, 4));
      v = fmaxf(v, __shfl_xor(v, 8));
      tm[i] = v;
    }
    bool need = (tm[0] > m_r[0] + 8.f) | (tm[1] > m_r[1] + 8.f) |
                (tm[2] > m_r[2] + 8.f) | (tm[3] > m_r[3] + 8.f);
    if (__any(need)) {
      float sc[4];
#pragma unroll
      for (int i = 0; i < 4; ++i) {
        float mn = fmaxf(m_r[i], tm[i]);
        sc[i] = __expf(m_r[i] - mn);
        m_r[i] = mn;
        l_acc[i] *= sc[i];
      }
#pragma unroll
      for (int j = 0; j < 16; ++j) {
#pragma unroll
        for (int i = 0; i < 4; ++i) o_acc[j][i] *= sc[i];
      }
    }
    // P -> bf16 -> p_lds (l comes from ones-MFMA below)
    u16* pl = p_lds[wid];
#pragma unroll
    for (int i = 0; i < 4; ++i) {
      float p0 = __expf(sa0[i] - m_r[i]);
      float p1 = __expf(sa1[i] - m_r[i]);
      int row = (lane >> 4) * 4 + i;
      pl[row * 40 + (lane & 15)] = f2bf(p0);
      pl[row * 40 + 16 + (lane & 15)] = f2bf(p1);
    }
    u16x8 pa = ld8(&pl[(lane & 15) * 40 + (lane >> 4) * 8]);
    __builtin_amdgcn_s_setprio(1);
    l_acc = mfma16(pa, ones, l_acc);  // row sums of P
#pragma unroll
    for (int cf = 0; cf < 16; ++cf) {
      int col = cf * 16 + (lane & 15);
      u16x8 bv = ld8(&lds_v[col * 32 + (((lane >> 4) ^ ((col >> 1) & 3)) << 3)]);
      o_acc[cf] = mfma16(pa, bv, o_acc[cf]);
    }
    __builtin_amdgcn_s_setprio(0);
  }

  float rl[4];
#pragma unroll
  for (int i = 0; i < 4; ++i) rl[i] = 1.f / l_acc[i];
  u16* Pout = (split == 0) ? P0 : (split == 1) ? P1 : (split == 2) ? P2 : P3;
#pragma unroll
  for (int cf = 0; cf < 16; ++cf) {
#pragma unroll
    for (int i = 0; i < 4; ++i) {
      int q = qbase + (lane >> 4) * 4 + i;
      int c2 = cf * 16 + (lane & 15);
      Pout[(size_t)(bb + q) * C + c2] = f2bf(o_acc[cf][i] * rl[i]);
    }
  }
  if ((lane & 15) == 0) {
#pragma unroll
    for (int i = 0; i < 4; ++i) {
      int q = qbase + (lane >> 4) * 4 + i;
      ML[split * BN + bb + q] = m_r[i];
      ML[(4 + split) * BN + bb + q] = l_acc[i];
    }
  }
}

// ---------------------------------------------------------------------------
// out = x*(1+gatt+sigmoid(sp0+sp1+s2b)) + local + anchor + merge4(P0..P3;ML)
__global__ __launch_bounds__(256) void compose_kernel(
    const float* __restrict__ x, const float* __restrict__ gatt,
    const u16* __restrict__ sp0, const u16* __restrict__ sp1,
    const float* __restrict__ s2b, const u16* __restrict__ localT,
    const u16* __restrict__ anchT, const u16* __restrict__ P0,
    const u16* __restrict__ P1, const u16* __restrict__ P2,
    const u16* __restrict__ P3, const float* __restrict__ ML,
    float* __restrict__ out) {
  const int b = blockIdx.y;
  const int p0 = blockIdx.x * 32;
  const int t = threadIdx.x;
  const int bb = b * N;
  __shared__ __align__(16) u16 lsA[32 * 72], lsL[32 * 72], lsO[32 * 72];
  __shared__ float aw[4][32];
  if (t < 32) {
    int gq = bb + p0 + t;
    float m0 = ML[gq], m1 = ML[BN + gq], m2 = ML[2 * BN + gq],
          m3 = ML[3 * BN + gq];
    float M = fmaxf(fmaxf(m0, m1), fmaxf(m2, m3));
    float w0 = ML[4 * BN + gq] * __expf(m0 - M);
    float w1 = ML[5 * BN + gq] * __expf(m1 - M);
    float w2 = ML[6 * BN + gq] * __expf(m2 - M);
    float w3 = ML[7 * BN + gq] * __expf(m3 - M);
    float inv = 1.f / (w0 + w1 + w2 + w3);
    aw[0][t] = w0 * inv;
    aw[1][t] = w1 * inv;
    aw[2][t] = w2 * inv;
    aw[3][t] = w3 * inv;
  }
#pragma unroll 1
  for (int cc = 0; cc < 4; ++cc) {
    const int c0 = cc * 64;
    __syncthreads();
    {
      int r = t >> 3, s = t & 7;
      size_t g = (size_t)(bb + p0 + r) * C + c0 + s * 8;
      u16x8 q0 = ld8(sp0 + g), q1 = ld8(sp1 + g), sa8;
#pragma unroll
      for (int j = 0; j < 8; ++j) {
        float v = bf2f(q0[j]) + bf2f(q1[j]) + s2b[c0 + s * 8 + j];
        sa8[j] = f2bf(1.f / (1.f + __expf(-v)));
      }
      st8(&lsA[r * 72 + s * 8], sa8);
      st8(&lsL[r * 72 + s * 8], ld8(localT + g));
      u16x8 a0 = ld8(P0 + g), a1 = ld8(P1 + g), a2 = ld8(P2 + g),
            a3 = ld8(P3 + g), an = ld8(anchT + g);
      float w0 = aw[0][r], w1 = aw[1][r], w2 = aw[2][r], w3 = aw[3][r];
      u16x8 om;
#pragma unroll
      for (int j = 0; j < 8; ++j)
        om[j] = f2bf(w0 * bf2f(a0[j]) + w1 * bf2f(a1[j]) + w2 * bf2f(a2[j]) +
                     w3 * bf2f(a3[j]) + bf2f(an[j]));
      st8(&lsO[r * 72 + s * 8], om);
    }
    __syncthreads();
    int pl = t & 31, cg = t >> 5;
    int p = p0 + pl;
#pragma unroll
    for (int j = 0; j < 8; ++j) {
      int c2 = c0 + cg * 8 + j;
      size_t xi = ((size_t)b * C + c2) * N + p;
      float xv = x[xi];
      float sa = bf2f(lsA[pl * 72 + (c2 - c0)]);
      float lf = bf2f(lsL[pl * 72 + (c2 - c0)]);
      float om = bf2f(lsO[pl * 72 + (c2 - c0)]);
      float ga = gatt[b * 256 + c2];
      out[xi] = xv * (1.f + ga + sa) + lf + om;
    }
  }
}

// ---------------------------------------------------------------------------
extern "C" void kernel_launch(void* const* d_in, const int* in_sizes, int n_in,
                              void* d_out, int out_size, void* d_ws,
                              size_t ws_size, hipStream_t stream) {
  (void)in_sizes; (void)n_in; (void)out_size; (void)ws_size;
  const float* x   = (const float*)d_in[0];
  const float* wq  = (const float*)d_in[1];
  const float* bq  = (const float*)d_in[2];
  const float* wk  = (const float*)d_in[3];
  const float* bk  = (const float*)d_in[4];
  const float* wv  = (const float*)d_in[5];
  const float* bv  = (const float*)d_in[6];
  const float* wa  = (const float*)d_in[7];
  const float* ba  = (const float*)d_in[8];
  const float* g1w = (const float*)d_in[9];
  const float* g1b = (const float*)d_in[10];
  const float* g2w = (const float*)d_in[11];
  const float* g2b = (const float*)d_in[12];
  const float* s1w = (const float*)d_in[13];
  const float* s1b = (const float*)d_in[14];
  const float* s2w = (const float*)d_in[15];
  const float* s2b = (const float*)d_in[16];
  const float* lw  = (const float*)d_in[17];
  const float* lb  = (const float*)d_in[18];
  float* out = (float*)d_out;

  char* w = (char*)d_ws;
  const size_t SZB = (size_t)8 * N * C * sizeof(u16);          // 9,437,184 B
  const size_t SZXP = (size_t)8 * XPAD_ROWS * C * sizeof(u16); // 11,943,936 B
  const size_t SZSP = (size_t)8 * SPAD_ROWS * C * sizeof(u16); // 10,616,832 B
  u16* xhiT   = (u16*)(w + 0 * SZB);   // input xT
  u16* sp0    = (u16*)(w + 1 * SZB);   // s2 partial 0
  u16* sp1    = (u16*)(w + 2 * SZB);   // s2 partial 1
  u16* qhiT   = (u16*)(w + 3 * SZB);
  u16* khiT   = (u16*)(w + 4 * SZB);
  u16* vbuf   = (u16*)(w + 5 * SZB);
  u16* localT = (u16*)(w + 6 * SZB);
  u16* OTb    = (u16*)(w + 7 * SZB);   // anchor
  u16* Pf0    = (u16*)(w + 8 * SZB);   // flash partial 0
  u16* Pf1    = (u16*)(w + 9 * SZB);   // flash partial 1
  u16* xpad   = (u16*)(w + 10 * SZB);             // -> flash partial 2
  u16* sbpad  = (u16*)(w + 10 * SZB + SZXP);      // -> flash partial 3
  char* wp = w + 10 * SZB + SZXP + SZSP;
  u16* wqh   = (u16*)(wp + 0);
  u16* wkh   = (u16*)(wp + 131072);
  u16* wvb   = (u16*)(wp + 262144);
  u16* wab   = (u16*)(wp + 393216);
  u16* s1rep = (u16*)(wp + 524288);
  u16* s2rep = (u16*)(wp + 1441792);
  u16* lwrep = (u16*)(wp + 2359296);
  float* mb    = (float*)(wp + 3538944);
  float* gattb = (float*)(wp + 3547136);
  float* ML    = (float*)(wp + 3555328);  // 8*BN floats

  // 1: prep (zero pads + weights + mean)
  prep_kernel<<<1984, 256, 0, stream>>>(x, wq, wk, wv, wa, s1w, s2w, lw,
                                        xpad, sbpad, wqh, wkh, wvb, wab,
                                        s1rep, s2rep, lwrep, mb);
  // 2: transpose + bf16 cast (+ padded copy)
  split_x_kernel<<<dim3(36, 4, 8), 256, 0, stream>>>(x, xhiT, xpad);
  // 3: squeeze-excite gate
  global_kernel<<<8, 256, 0, stream>>>(mb, g1w, g1b, g2w, g2b, gattb);

  // 4: one fused dispatch: local(3x3), s1(1x7), q, k, v, anchor
  OpPack pk;
  pk.d[0] = {xpad, lwrep, lb, localT, 3, 1, 0, 0, XPAD_ROWS, 54, 3, 0, 36};
  pk.d[1] = {xpad, s1rep, s1b, sbpad,  1, 1, 0, 1, XPAD_ROWS, 54, 3, 0, 28};
  pk.d[2] = {xhiT, wqh,   bq, qhiT,    0, 0, 0, 0, N, 0, 0, 0, 4};
  pk.d[3] = {xhiT, wkh,   bk, khiT,    0, 0, 0, 0, N, 0, 0, 0, 4};
  pk.d[4] = {xhiT, wvb,   bv, vbuf,    0, 0, 1, 0, N, 0, 0, 0, 4};
  pk.d[5] = {xhiT, wab,   ba, OTb,     0, 0, 0, 0, N, 0, 0, 0, 4};
  pk.chunk = 1728 / 8;
  pk.ny = 12;
  fused_gemm_kernel<<<dim3(1728), 256, 0, stream>>>(pk);

  // 5: spectral second conv, split-K=2 raw partials -> sp0/sp1
  OpPack pk2;
  pk2.d[0] = {sbpad, s2rep, nullptr, sp0, 2, 0, 0, 0, SPAD_ROWS, 48, 0, 0, 14};
  pk2.d[1] = {sbpad, s2rep, nullptr, sp1, 2, 0, 0, 0, SPAD_ROWS, 48, 0, 14, 28};
  pk2.chunk = 576 / 8;
  pk2.ny = 4;
  fused_gemm_kernel<<<dim3(576), 256, 0, stream>>>(pk2);

  // 6: flash attention, split-K=4 (partials into dead buffers)
  flash_kernel<<<dim3(36, 8, 4), 256, 0, stream>>>(
      qhiT, khiT, vbuf, Pf0, Pf1, xpad, sbpad, ML);

  // 7: final composition (s2 finish + split-K merge + anchor)
  compose_kernel<<<dim3(72, 8), 256, 0, stream>>>(
      x, gattb, sp0, sp1, s2b, localT, OTb, Pf0, Pf1, xpad, sbpad, ML, out);
}

// Round 17
// 255.058 us; speedup vs baseline: 1.3117x; 1.3117x over previous
//
#include <hip/hip_runtime.h>

// HierarchicalAttentionModule on MI355X (gfx950).
// B=8, C=256, H=W=48, N=2304. All inputs fp32, output fp32.
// Round 17: round-13 base (251.7us best) + flash KVBLK 32->64 (9 tiles,
// half the barriers/prefetch round-trips, longer MFMA clusters) at the
// proven (256,2) bound. r16's (256,3) spilled (VGPR->84, scratch writes)
// confirming 2 blocks/CU is the register-feasible occupancy for flash.

typedef unsigned short u16;
typedef unsigned int u32;
typedef __attribute__((ext_vector_type(8))) u16 u16x8;
typedef __attribute__((ext_vector_type(4))) float f32x4;
typedef __attribute__((ext_vector_type(4))) float f4;
typedef __attribute__((ext_vector_type(8))) __bf16 bf16x8;

#define DEVINL __device__ __forceinline__

constexpr int C = 256;
constexpr int N = 2304;
constexpr int HW = 48;
constexpr int BSTRIDE = C * N;   // elements per batch
constexpr int BN = 8 * N;        // 18432
constexpr int XPAD_ROWS = 54 * 54;  // 2916 padded positions (xpad)
constexpr int SPAD_ROWS = 54 * 48;  // 2592 padded positions (sb_pad)

DEVINL u16 f2bf(float f) {
  u32 u = __builtin_bit_cast(u32, f);
  u += 0x7fffu + ((u >> 16) & 1u);
  return (u16)(u >> 16);
}
DEVINL float bf2f(u16 h) {
  u32 u = ((u32)h) << 16;
  return __builtin_bit_cast(float, u);
}
DEVINL u16x8 ld8(const u16* p) { return *reinterpret_cast<const u16x8*>(p); }
DEVINL void st8(u16* p, u16x8 v) { *reinterpret_cast<u16x8*>(p) = v; }
DEVINL f32x4 mfma16(u16x8 a, u16x8 b, f32x4 c) {
  return __builtin_amdgcn_mfma_f32_16x16x32_bf16(
      __builtin_bit_cast(bf16x8, a), __builtin_bit_cast(bf16x8, b), c, 0, 0, 0);
}
DEVINL void gl16(const void* g, void* l) {
  __builtin_amdgcn_global_load_lds(
      (const __attribute__((address_space(1))) u32*)g,
      (__attribute__((address_space(3))) u32*)l, 16, 0, 0);
}

// ---------------------------------------------------------------------------
// prep: blocks [0,704) zero xpad+sbpad; [704,960) weight casts/repacks;
//       [960,1984) spatial mean (2 rows per block).
__global__ __launch_bounds__(256) void prep_kernel(
    const float* __restrict__ x,
    const float* __restrict__ wq, const float* __restrict__ wk,
    const float* __restrict__ wv, const float* __restrict__ wa,
    const float* __restrict__ s1w, const float* __restrict__ s2w,
    const float* __restrict__ lw,
    u16* __restrict__ xpad, u16* __restrict__ sbpad,
    u16* __restrict__ wqh, u16* __restrict__ wkh,
    u16* __restrict__ wvb, u16* __restrict__ wab,
    u16* __restrict__ s1rep, u16* __restrict__ s2rep, u16* __restrict__ lwrep,
    float* __restrict__ mb) {
  const int blk = blockIdx.x;
  const int t = threadIdx.x;
  if (blk < 704) {
    const long CX = (long)8 * XPAD_ROWS * C / 8;
    const long CS = (long)8 * SPAD_ROWS * C / 8;
    u16x8 z = {0, 0, 0, 0, 0, 0, 0, 0};
    for (long k = (long)blk * 256 + t; k < CX + CS; k += 704L * 256) {
      if (k < CX) st8(xpad + k * 8, z);
      else st8(sbpad + (k - CX) * 8, z);
    }
  } else if (blk < 960) {
    int base = (blk - 704) * 256 + t;  // [0, 65536)
    wqh[base] = f2bf(wq[base]);
    wkh[base] = f2bf(wk[base]);
    wvb[base] = f2bf(wv[base]);
    wab[base] = f2bf(wa[base]);
    size_t b7 = (size_t)base * 7, b9 = (size_t)base * 9;
#pragma unroll
    for (int tp = 0; tp < 7; ++tp) s1rep[tp * 65536 + base] = f2bf(s1w[b7 + tp]);
#pragma unroll
    for (int tp = 0; tp < 7; ++tp) s2rep[tp * 65536 + base] = f2bf(s2w[b7 + tp]);
#pragma unroll
    for (int tp = 0; tp < 9; ++tp) lwrep[tp * 65536 + base] = f2bf(lw[b9 + tp]);
  } else {
    __shared__ float ws4[4];
    int r0 = (blk - 960) * 2;
#pragma unroll
    for (int rr = 0; rr < 2; ++rr) {
      const float* p = x + (size_t)(r0 + rr) * N;
      float s = 0.f;
      for (int i = t; i < N; i += 256) s += p[i];
#pragma unroll
      for (int off = 32; off >= 1; off >>= 1) s += __shfl_xor(s, off);
      if ((t & 63) == 0) ws4[t >> 6] = s;
      __syncthreads();
      if (t == 0) mb[r0 + rr] = (ws4[0] + ws4[1] + ws4[2] + ws4[3]) * (1.f / N);
      __syncthreads();
    }
  }
}

// ---------------------------------------------------------------------------
// x [B][C][N] fp32 -> xT bf16 [B][N][C]  +  xpad_hi [B][2916][C]
__global__ __launch_bounds__(256) void split_x_kernel(
    const float* __restrict__ x, u16* __restrict__ xhi,
    u16* __restrict__ xpad) {
  const int b = blockIdx.z;
  const int p0 = blockIdx.x * 64;
  const int c0 = blockIdx.y * 64;
  const int tid = threadIdx.x;
  __shared__ float tile[64][65];
#pragma unroll
  for (int it = 0; it < 4; ++it) {
    int idx = it * 256 + tid;
    int cr = idx >> 4, pc = (idx & 15) * 4;
    f4 v = *reinterpret_cast<const f4*>(&x[((size_t)b * C + c0 + cr) * N + p0 + pc]);
    tile[cr][pc] = v[0];
    tile[cr][pc + 1] = v[1];
    tile[cr][pc + 2] = v[2];
    tile[cr][pc + 3] = v[3];
  }
  __syncthreads();
#pragma unroll
  for (int it = 0; it < 2; ++it) {
    int idx = it * 256 + tid;
    int pr = idx >> 3, cg = (idx & 7) * 8;
    u16x8 h8;
#pragma unroll
    for (int j = 0; j < 8; ++j) h8[j] = f2bf(tile[cg + j][pr]);
    int p = p0 + pr;
    size_t o = ((size_t)b * N + p) * C + c0 + cg;
    st8(xhi + o, h8);
    int hh = p / HW, ww = p - hh * HW;
    size_t op = ((size_t)b * XPAD_ROWS + (size_t)(hh + 3) * 54 + ww + 3) * C + c0 + cg;
    st8(xpad + op, h8);
  }
}

__global__ __launch_bounds__(256) void global_kernel(
    const float* __restrict__ m, const float* __restrict__ g1w,
    const float* __restrict__ g1b, const float* __restrict__ g2w,
    const float* __restrict__ g2b, float* __restrict__ gatt) {
  int b = blockIdx.x, t = threadIdx.x;
  __shared__ float ms[256], hid[32];
  ms[t] = m[b * 256 + t];
  __syncthreads();
  if (t < 32) {
    float s = g1b[t];
    const float* wr = g1w + t * 256;
    for (int c2 = 0; c2 < 256; ++c2) s += ms[c2] * wr[c2];
    hid[t] = fmaxf(s, 0.f);
  }
  __syncthreads();
  float s = g2b[t];
#pragma unroll
  for (int j = 0; j < 32; ++j) s += hid[j] * g2w[t * 32 + j];
  gatt[b * 256 + t] = 1.f / (1.f + __expf(-s));
}

// ---------------------------------------------------------------------------
// Descriptor-driven fused GEMM (round-13 single-buffer m97 structure).
struct OpDesc {
  const u16* Xh;
  const u16* W;
  const float* bias;  // nullptr -> raw partial (no bias/act)
  u16* o0;
  int tk;      // 0 none, 1 = 1x7, 2 = 7x1, 3 = 3x3
  int act;     // 0 none, 1 relu, 2 sigmoid
  int outn;    // 0: out[pos][o], 1: out[o][pos]
  int opad;    // output to sb_pad geometry
  int ips;     // input rows per batch
  int idy;     // row delta for dy=+1
  int iox;     // column origin
  int s0, s1;  // step range over flattened (tap, ks)
};
struct OpPack {
  OpDesc d[6];
  int chunk;  // nwg/8 for XCD swizzle
  int ny;
};

__global__ __launch_bounds__(256, 3) void fused_gemm_kernel(OpPack pk) {
  const int swz = (blockIdx.x & 7) * pk.chunk + (blockIdx.x >> 3);
  const int xt = swz % 18;
  const int rest = swz / 18;
  const int y = rest % pk.ny;
  const int z = rest / pk.ny;
  const OpDesc dd = pk.d[y >> 1];
  const int mbase = xt * 128;
  const int nbase = (y & 1) * 128;
  const int tid = threadIdx.x;
  const int lane = tid & 63;
  const int wid = tid >> 6;
  const int wm = wid >> 1, wn = wid & 1;
  const int tk = dd.tk;

  __shared__ __align__(16) u16 ldsX[128 * 64];
  __shared__ __align__(16) u16 ldsW[128 * 64];

  f32x4 acc[4][4];
#pragma unroll
  for (int m = 0; m < 4; ++m)
#pragma unroll
    for (int n = 0; n < 4; ++n) acc[m][n] = f32x4{0.f, 0.f, 0.f, 0.f};

  size_t xrow[4], wrow[4];
#pragma unroll
  for (int it = 0; it < 4; ++it) {
    int idx = it * 256 + tid;
    int rr = idx >> 3, ss = idx & 7;
    int perm = ss ^ (rr & 7);
    int p = mbase + rr;
    if (tk == 0) {
      xrow[it] = ((size_t)z * N + p) * 512 + (size_t)perm * 16;
    } else {
      int hh = p / HW, ww = p - hh * HW;
      xrow[it] = ((size_t)z * dd.ips + (size_t)(hh + 3) * dd.idy + ww + dd.iox) * 512 +
                 (size_t)perm * 16;
    }
    wrow[it] = ((size_t)(nbase + rr)) * 512 + (size_t)perm * 16;
  }
  int aoff[2][4], boff[2][4];
#pragma unroll
  for (int kk = 0; kk < 2; ++kk) {
    int seg = kk * 4 + (lane >> 4);
#pragma unroll
    for (int m = 0; m < 4; ++m) {
      int ra = wm * 64 + m * 16 + (lane & 15);
      aoff[kk][m] = ra * 64 + ((seg ^ (ra & 7)) << 3);
      int rb = wn * 64 + m * 16 + (lane & 15);
      boff[kk][m] = rb * 64 + ((seg ^ (rb & 7)) << 3);
    }
  }

  auto stage = [&](int tap, int ks) {
    const char* xs = (const char*)dd.Xh;
    const char* wsrc = (const char*)dd.W + (size_t)tap * 131072;
    int tsh = 0;
    if (tk == 1) tsh = tap - 3;
    else if (tk == 2) tsh = (tap - 3) * dd.idy;
    else if (tk == 3) tsh = (tap / 3 - 1) * dd.idy + (tap % 3 - 1);
    const long xadd = (long)tsh * 512 + ks * 128;
    const long wadd = ks * 128;
#pragma unroll
    for (int it = 0; it < 4; ++it) {
      gl16(xs + xrow[it] + xadd, &ldsX[(it * 4 + wid) * 512]);
      gl16(wsrc + wrow[it] + wadd, &ldsW[(it * 4 + wid) * 512]);
    }
  };

  int t0 = dd.s0;
  int cks = t0 & 3;
  int ctap = t0 >> 2;
  stage(ctap, cks);

#pragma unroll 1
  for (int t = dd.s0; t < dd.s1; ++t) {
    __syncthreads();  // staging drained & visible
    const u16* Alds = dd.outn ? ldsW : ldsX;
    const u16* Blds = dd.outn ? ldsX : ldsW;
#pragma unroll
    for (int kk = 0; kk < 2; ++kk) {
      u16x8 af[4], bfr[4];
#pragma unroll
      for (int m = 0; m < 4; ++m) af[m] = ld8(&Alds[aoff[kk][m]]);
#pragma unroll
      for (int n = 0; n < 4; ++n) bfr[n] = ld8(&Blds[boff[kk][n]]);
      __builtin_amdgcn_s_setprio(1);
#pragma unroll
      for (int m = 0; m < 4; ++m)
#pragma unroll
        for (int n = 0; n < 4; ++n)
          acc[m][n] = mfma16(af[m], bfr[n], acc[m][n]);
      __builtin_amdgcn_s_setprio(0);
    }
    __syncthreads();  // all LDS reads done before next stage overwrites
    if (t + 1 < dd.s1) {
      if (++cks == 4) { cks = 0; ++ctap; }
      stage(ctap, cks);
    }
  }

  const int r4 = (lane >> 4) * 4, cl = lane & 15;
  const size_t xb = (size_t)z * BSTRIDE;
#pragma unroll
  for (int m = 0; m < 4; ++m) {
#pragma unroll
    for (int n = 0; n < 4; ++n) {
#pragma unroll
      for (int i = 0; i < 4; ++i) {
        int lrow = wm * 64 + m * 16 + r4 + i;
        int lcol = wn * 64 + n * 16 + cl;
        int o = dd.outn ? (nbase + lrow) : (nbase + lcol);
        int pos = dd.outn ? (mbase + lcol) : (mbase + lrow);
        float v = acc[m][n][i];
        if (dd.bias) {
          v += dd.bias[o];
          if (dd.act == 1) v = fmaxf(v, 0.f);
          else if (dd.act == 2) v = 1.f / (1.f + __expf(-v));
        }
        size_t oi;
        if (dd.opad) {
          int hh = pos / HW, ww = pos - hh * HW;
          oi = ((size_t)z * SPAD_ROWS + (size_t)(hh + 3) * 48 + ww) * C + o;
        } else {
          oi = xb + (dd.outn ? ((size_t)o * N + pos) : ((size_t)pos * C + o));
        }
        dd.o0[oi] = f2bf(v);
      }
    }
  }
}

// ---------------------------------------------------------------------------
// Flash attention, split-K=4, KVBLK=64 (9 tiles/block: half the barriers of
// round-13). 1-term QK; K/V register prefetch; ones-MFMA row-sum; defer-max.
// (256,2) — the proven non-spilling bound.
__global__ __launch_bounds__(256, 2) void flash_kernel(
    const u16* __restrict__ Qhi, const u16* __restrict__ Khi,
    const u16* __restrict__ Vb, u16* __restrict__ P0, u16* __restrict__ P1,
    u16* __restrict__ P2, u16* __restrict__ P3, float* __restrict__ ML) {
  const int b = blockIdx.y;
  const int split = blockIdx.z;
  const int q0 = blockIdx.x * 64;
  const int tid = threadIdx.x;
  const int lane = tid & 63;
  const int wid = tid >> 6;
  const int qbase = q0 + wid * 16;
  const int bb = b * N;
  const u16* Vp = Vb + (size_t)b * BSTRIDE;

  __shared__ __align__(16) u16 lds_kh[64 * 256];   // 32 KB
  __shared__ __align__(16) u16 lds_v[256 * 64];    // 32 KB
  __shared__ __align__(16) u16 p_lds[4][16 * 72];  // 9 KB

  u16x8 qfh[8];
  {
    size_t base = ((size_t)(bb + qbase + (lane & 15))) * C + (lane >> 4) * 8;
#pragma unroll
    for (int kc = 0; kc < 8; ++kc) qfh[kc] = ld8(Qhi + base + kc * 32);
  }
  const u16x8 ones = {0x3F80, 0x3F80, 0x3F80, 0x3F80,
                      0x3F80, 0x3F80, 0x3F80, 0x3F80};  // bf16 1.0

  f32x4 o_acc[16];
#pragma unroll
  for (int j = 0; j < 16; ++j) o_acc[j] = f32x4{0.f, 0.f, 0.f, 0.f};
  float m_r[4] = {-1e30f, -1e30f, -1e30f, -1e30f};
  f32x4 l_acc = {0.f, 0.f, 0.f, 0.f};

  // staging: 64x256 K (8 iters) + 256x64 V (8 iters)
  u16x8 skh[8], sv[8];
  const int kt0 = split * 9;
  auto issue = [&](int kt) {
    const int k0 = kt * 64;
#pragma unroll
    for (int it = 0; it < 8; ++it) {
      int idx = it * 256 + tid;
      int r = idx >> 5, s = idx & 31;     // K row [0,64), col-chunk [0,32)
      skh[it] = ld8(Khi + (size_t)(bb + k0 + r) * C + s * 8);
      int c2 = idx >> 3, s2 = idx & 7;    // V chan [0,256), k-chunk [0,8)
      sv[it] = ld8(Vp + (size_t)c2 * N + k0 + s2 * 8);
    }
  };
  issue(kt0);

#pragma unroll 1
  for (int t2 = 0; t2 < 9; ++t2) {
    __syncthreads();
#pragma unroll
    for (int it = 0; it < 8; ++it) {
      int idx = it * 256 + tid;
      int r = idx >> 5, s = idx & 31;
      st8(&lds_kh[r * 256 + ((s ^ (r & 7)) << 3)], skh[it]);
      int c2 = idx >> 3, s2 = idx & 7;
      st8(&lds_v[c2 * 64 + ((s2 ^ ((c2 >> 1) & 7)) << 3)], sv[it]);
    }
    __syncthreads();
    if (t2 < 8) issue(kt0 + t2 + 1);

    // 1-term QK^T over 64 key columns: 4 score fragments
    f32x4 sa[4];
#pragma unroll
    for (int f = 0; f < 4; ++f) sa[f] = f32x4{0.f, 0.f, 0.f, 0.f};
    __builtin_amdgcn_s_setprio(1);
#pragma unroll
    for (int kc = 0; kc < 8; ++kc) {
      int seg = kc * 4 + (lane >> 4);
#pragma unroll
      for (int f = 0; f < 4; ++f) {
        int r = f * 16 + (lane & 15);
        u16x8 bfr = ld8(&lds_kh[r * 256 + ((seg ^ (r & 7)) << 3)]);
        sa[f] = mfma16(qfh[kc], bfr, sa[f]);
      }
    }
    __builtin_amdgcn_s_setprio(0);

    // online softmax with defer-max (THR=8)
    float tm[4];
#pragma unroll
    for (int i = 0; i < 4; ++i) {
      float v = fmaxf(fmaxf(sa[0][i], sa[1][i]), fmaxf(sa[2][i], sa[3][i]));
      v = fmaxf(v, __shfl_xor(v, 1));
      v = fmaxf(v, __shfl_xor(v, 2));
      v = fmaxf(v, __shfl_xor(v, 4));
      v = fmaxf(v, __shfl_xor(v, 8));
      tm[i] = v;
    }
    bool need = (tm[0] > m_r[0] + 8.f) | (tm[1] > m_r[1] + 8.f) |
                (tm[2] > m_r[2] + 8.f) | (tm[3] > m_r[3] + 8.f);
    if (__any(need)) {
      float sc[4];
#pragma unroll
      for (int i = 0; i < 4; ++i) {
        float mn = fmaxf(m_r[i], tm[i]);
        sc[i] = __expf(m_r[i] - mn);
        m_r[i] = mn;
        l_acc[i] *= sc[i];
      }
#pragma unroll
      for (int j = 0; j < 16; ++j) {
#pragma unroll
        for (int i = 0; i < 4; ++i) o_acc[j][i] *= sc[i];
      }
    }
    // P -> bf16 -> p_lds [16 q-rows][64 k-cols], stride 72
    u16* pl = p_lds[wid];
#pragma unroll
    for (int i = 0; i < 4; ++i) {
      int row = (lane >> 4) * 4 + i;
#pragma unroll
      for (int f = 0; f < 4; ++f)
        pl[row * 72 + f * 16 + (lane & 15)] = f2bf(__expf(sa[f][i] - m_r[i]));
    }
    // PV: two K=32 passes (pa0 = k 0..31, pa1 = k 32..63)
    u16x8 pa0 = ld8(&pl[(lane & 15) * 72 + (lane >> 4) * 8]);
    u16x8 pa1 = ld8(&pl[(lane & 15) * 72 + 32 + (lane >> 4) * 8]);
    __builtin_amdgcn_s_setprio(1);
    l_acc = mfma16(pa0, ones, l_acc);
    l_acc = mfma16(pa1, ones, l_acc);
#pragma unroll
    for (int cf = 0; cf < 16; ++cf) {
      int col = cf * 16 + (lane & 15);
      int swv = (col >> 1) & 7;
      u16x8 bv0 = ld8(&lds_v[col * 64 + (((lane >> 4) ^ swv) << 3)]);
      o_acc[cf] = mfma16(pa0, bv0, o_acc[cf]);
      u16x8 bv1 = ld8(&lds_v[col * 64 + (((4 + (lane >> 4)) ^ swv) << 3)]);
      o_acc[cf] = mfma16(pa1, bv1, o_acc[cf]);
    }
    __builtin_amdgcn_s_setprio(0);
  }

  float rl[4];
#pragma unroll
  for (int i = 0; i < 4; ++i) rl[i] = 1.f / l_acc[i];
  u16* Pout = (split == 0) ? P0 : (split == 1) ? P1 : (split == 2) ? P2 : P3;
#pragma unroll
  for (int cf = 0; cf < 16; ++cf) {
#pragma unroll
    for (int i = 0; i < 4; ++i) {
      int q = qbase + (lane >> 4) * 4 + i;
      int c2 = cf * 16 + (lane & 15);
      Pout[(size_t)(bb + q) * C + c2] = f2bf(o_acc[cf][i] * rl[i]);
    }
  }
  if ((lane & 15) == 0) {
#pragma unroll
    for (int i = 0; i < 4; ++i) {
      int q = qbase + (lane >> 4) * 4 + i;
      ML[split * BN + bb + q] = m_r[i];
      ML[(4 + split) * BN + bb + q] = l_acc[i];
    }
  }
}

// ---------------------------------------------------------------------------
// out = x*(1+gatt+sigmoid(sp0+sp1+s2b)) + local + anchor + merge4(P0..P3;ML)
__global__ __launch_bounds__(256) void compose_kernel(
    const float* __restrict__ x, const float* __restrict__ gatt,
    const u16* __restrict__ sp0, const u16* __restrict__ sp1,
    const float* __restrict__ s2b, const u16* __restrict__ localT,
    const u16* __restrict__ anchT, const u16* __restrict__ P0,
    const u16* __restrict__ P1, const u16* __restrict__ P2,
    const u16* __restrict__ P3, const float* __restrict__ ML,
    float* __restrict__ out) {
  const int b = blockIdx.y;
  const int p0 = blockIdx.x * 32;
  const int t = threadIdx.x;
  const int bb = b * N;
  __shared__ __align__(16) u16 lsA[32 * 72], lsL[32 * 72], lsO[32 * 72];
  __shared__ float aw[4][32];
  if (t < 32) {
    int gq = bb + p0 + t;
    float m0 = ML[gq], m1 = ML[BN + gq], m2 = ML[2 * BN + gq],
          m3 = ML[3 * BN + gq];
    float M = fmaxf(fmaxf(m0, m1), fmaxf(m2, m3));
    float w0 = ML[4 * BN + gq] * __expf(m0 - M);
    float w1 = ML[5 * BN + gq] * __expf(m1 - M);
    float w2 = ML[6 * BN + gq] * __expf(m2 - M);
    float w3 = ML[7 * BN + gq] * __expf(m3 - M);
    float inv = 1.f / (w0 + w1 + w2 + w3);
    aw[0][t] = w0 * inv;
    aw[1][t] = w1 * inv;
    aw[2][t] = w2 * inv;
    aw[3][t] = w3 * inv;
  }
#pragma unroll 1
  for (int cc = 0; cc < 4; ++cc) {
    const int c0 = cc * 64;
    __syncthreads();
    {
      int r = t >> 3, s = t & 7;
      size_t g = (size_t)(bb + p0 + r) * C + c0 + s * 8;
      u16x8 q0 = ld8(sp0 + g), q1 = ld8(sp1 + g), sa8;
#pragma unroll
      for (int j = 0; j < 8; ++j) {
        float v = bf2f(q0[j]) + bf2f(q1[j]) + s2b[c0 + s * 8 + j];
        sa8[j] = f2bf(1.f / (1.f + __expf(-v)));
      }
      st8(&lsA[r * 72 + s * 8], sa8);
      st8(&lsL[r * 72 + s * 8], ld8(localT + g));
      u16x8 a0 = ld8(P0 + g), a1 = ld8(P1 + g), a2 = ld8(P2 + g),
            a3 = ld8(P3 + g), an = ld8(anchT + g);
      float w0 = aw[0][r], w1 = aw[1][r], w2 = aw[2][r], w3 = aw[3][r];
      u16x8 om;
#pragma unroll
      for (int j = 0; j < 8; ++j)
        om[j] = f2bf(w0 * bf2f(a0[j]) + w1 * bf2f(a1[j]) + w2 * bf2f(a2[j]) +
                     w3 * bf2f(a3[j]) + bf2f(an[j]));
      st8(&lsO[r * 72 + s * 8], om);
    }
    __syncthreads();
    int pl = t & 31, cg = t >> 5;
    int p = p0 + pl;
#pragma unroll
    for (int j = 0; j < 8; ++j) {
      int c2 = c0 + cg * 8 + j;
      size_t xi = ((size_t)b * C + c2) * N + p;
      float xv = x[xi];
      float sa = bf2f(lsA[pl * 72 + (c2 - c0)]);
      float lf = bf2f(lsL[pl * 72 + (c2 - c0)]);
      float om = bf2f(lsO[pl * 72 + (c2 - c0)]);
      float ga = gatt[b * 256 + c2];
      out[xi] = xv * (1.f + ga + sa) + lf + om;
    }
  }
}

// ---------------------------------------------------------------------------
extern "C" void kernel_launch(void* const* d_in, const int* in_sizes, int n_in,
                              void* d_out, int out_size, void* d_ws,
                              size_t ws_size, hipStream_t stream) {
  (void)in_sizes; (void)n_in; (void)out_size; (void)ws_size;
  const float* x   = (const float*)d_in[0];
  const float* wq  = (const float*)d_in[1];
  const float* bq  = (const float*)d_in[2];
  const float* wk  = (const float*)d_in[3];
  const float* bk  = (const float*)d_in[4];
  const float* wv  = (const float*)d_in[5];
  const float* bv  = (const float*)d_in[6];
  const float* wa  = (const float*)d_in[7];
  const float* ba  = (const float*)d_in[8];
  const float* g1w = (const float*)d_in[9];
  const float* g1b = (const float*)d_in[10];
  const float* g2w = (const float*)d_in[11];
  const float* g2b = (const float*)d_in[12];
  const float* s1w = (const float*)d_in[13];
  const float* s1b = (const float*)d_in[14];
  const float* s2w = (const float*)d_in[15];
  const float* s2b = (const float*)d_in[16];
  const float* lw  = (const float*)d_in[17];
  const float* lb  = (const float*)d_in[18];
  float* out = (float*)d_out;

  char* w = (char*)d_ws;
  const size_t SZB = (size_t)8 * N * C * sizeof(u16);          // 9,437,184 B
  const size_t SZXP = (size_t)8 * XPAD_ROWS * C * sizeof(u16); // 11,943,936 B
  const size_t SZSP = (size_t)8 * SPAD_ROWS * C * sizeof(u16); // 10,616,832 B
  u16* xhiT   = (u16*)(w + 0 * SZB);   // input xT
  u16* sp0    = (u16*)(w + 1 * SZB);   // s2 partial 0
  u16* sp1    = (u16*)(w + 2 * SZB);   // s2 partial 1
  u16* qhiT   = (u16*)(w + 3 * SZB);
  u16* khiT   = (u16*)(w + 4 * SZB);
  u16* vbuf   = (u16*)(w + 5 * SZB);
  u16* localT = (u16*)(w + 6 * SZB);
  u16* OTb    = (u16*)(w + 7 * SZB);   // anchor
  u16* Pf0    = (u16*)(w + 8 * SZB);   // flash partial 0
  u16* Pf1    = (u16*)(w + 9 * SZB);   // flash partial 1
  u16* xpad   = (u16*)(w + 10 * SZB);             // -> flash partial 2
  u16* sbpad  = (u16*)(w + 10 * SZB + SZXP);      // -> flash partial 3
  char* wp = w + 10 * SZB + SZXP + SZSP;
  u16* wqh   = (u16*)(wp + 0);
  u16* wkh   = (u16*)(wp + 131072);
  u16* wvb   = (u16*)(wp + 262144);
  u16* wab   = (u16*)(wp + 393216);
  u16* s1rep = (u16*)(wp + 524288);
  u16* s2rep = (u16*)(wp + 1441792);
  u16* lwrep = (u16*)(wp + 2359296);
  float* mb    = (float*)(wp + 3538944);
  float* gattb = (float*)(wp + 3547136);
  float* ML    = (float*)(wp + 3555328);  // 8*BN floats

  // 1: prep (zero pads + weights + mean)
  prep_kernel<<<1984, 256, 0, stream>>>(x, wq, wk, wv, wa, s1w, s2w, lw,
                                        xpad, sbpad, wqh, wkh, wvb, wab,
                                        s1rep, s2rep, lwrep, mb);
  // 2: transpose + bf16 cast (+ padded copy)
  split_x_kernel<<<dim3(36, 4, 8), 256, 0, stream>>>(x, xhiT, xpad);
  // 3: squeeze-excite gate
  global_kernel<<<8, 256, 0, stream>>>(mb, g1w, g1b, g2w, g2b, gattb);

  // 4: one fused dispatch: local(3x3), s1(1x7), q, k, v, anchor
  OpPack pk;
  pk.d[0] = {xpad, lwrep, lb, localT, 3, 1, 0, 0, XPAD_ROWS, 54, 3, 0, 36};
  pk.d[1] = {xpad, s1rep, s1b, sbpad,  1, 1, 0, 1, XPAD_ROWS, 54, 3, 0, 28};
  pk.d[2] = {xhiT, wqh,   bq, qhiT,    0, 0, 0, 0, N, 0, 0, 0, 4};
  pk.d[3] = {xhiT, wkh,   bk, khiT,    0, 0, 0, 0, N, 0, 0, 0, 4};
  pk.d[4] = {xhiT, wvb,   bv, vbuf,    0, 0, 1, 0, N, 0, 0, 0, 4};
  pk.d[5] = {xhiT, wab,   ba, OTb,     0, 0, 0, 0, N, 0, 0, 0, 4};
  pk.chunk = 1728 / 8;
  pk.ny = 12;
  fused_gemm_kernel<<<dim3(1728), 256, 0, stream>>>(pk);

  // 5: spectral second conv, split-K=2 raw partials -> sp0/sp1
  OpPack pk2;
  pk2.d[0] = {sbpad, s2rep, nullptr, sp0, 2, 0, 0, 0, SPAD_ROWS, 48, 0, 0, 14};
  pk2.d[1] = {sbpad, s2rep, nullptr, sp1, 2, 0, 0, 0, SPAD_ROWS, 48, 0, 14, 28};
  pk2.chunk = 576 / 8;
  pk2.ny = 4;
  fused_gemm_kernel<<<dim3(576), 256, 0, stream>>>(pk2);

  // 6: flash attention, split-K=4, KVBLK=64 (partials into dead buffers)
  flash_kernel<<<dim3(36, 8, 4), 256, 0, stream>>>(
      qhiT, khiT, vbuf, Pf0, Pf1, xpad, sbpad, ML);

  // 7: final composition (s2 finish + split-K merge + anchor)
  compose_kernel<<<dim3(72, 8), 256, 0, stream>>>(
      x, gattb, sp0, sp1, s2b, localT, OTb, Pf0, Pf1, xpad, sbpad, ML, out);
}

// Round 18
// 251.532 us; speedup vs baseline: 1.3301x; 1.0140x over previous
//
#include <hip/hip_runtime.h>

// HierarchicalAttentionModule on MI355X (gfx950).
// B=8, C=256, H=W=48, N=2304. All inputs fp32, output fp32.
// Round 18: FINAL — revert to round-13 exact (251.7us session best).
// Flash: split-K=4, QBLK=64, KVBLK=32, 1-term QK, reg prefetch, ones-MFMA
// row-sum, defer-max, (256,2). Fused GEMM: single-buffer m97 gl16 at (256,3).
// Subsequent experiments (r14 LDS-BW, r15 V-pad, r16 occupancy, r17 barrier
// halving) were all neutral-or-worse; this is the measured optimum.

typedef unsigned short u16;
typedef unsigned int u32;
typedef __attribute__((ext_vector_type(8))) u16 u16x8;
typedef __attribute__((ext_vector_type(4))) float f32x4;
typedef __attribute__((ext_vector_type(4))) float f4;
typedef __attribute__((ext_vector_type(8))) __bf16 bf16x8;

#define DEVINL __device__ __forceinline__

constexpr int C = 256;
constexpr int N = 2304;
constexpr int HW = 48;
constexpr int BSTRIDE = C * N;   // elements per batch
constexpr int BN = 8 * N;        // 18432
constexpr int XPAD_ROWS = 54 * 54;  // 2916 padded positions (xpad)
constexpr int SPAD_ROWS = 54 * 48;  // 2592 padded positions (sb_pad)

DEVINL u16 f2bf(float f) {
  u32 u = __builtin_bit_cast(u32, f);
  u += 0x7fffu + ((u >> 16) & 1u);
  return (u16)(u >> 16);
}
DEVINL float bf2f(u16 h) {
  u32 u = ((u32)h) << 16;
  return __builtin_bit_cast(float, u);
}
DEVINL u16x8 ld8(const u16* p) { return *reinterpret_cast<const u16x8*>(p); }
DEVINL void st8(u16* p, u16x8 v) { *reinterpret_cast<u16x8*>(p) = v; }
DEVINL f32x4 mfma16(u16x8 a, u16x8 b, f32x4 c) {
  return __builtin_amdgcn_mfma_f32_16x16x32_bf16(
      __builtin_bit_cast(bf16x8, a), __builtin_bit_cast(bf16x8, b), c, 0, 0, 0);
}
DEVINL void gl16(const void* g, void* l) {
  __builtin_amdgcn_global_load_lds(
      (const __attribute__((address_space(1))) u32*)g,
      (__attribute__((address_space(3))) u32*)l, 16, 0, 0);
}

// ---------------------------------------------------------------------------
// prep: blocks [0,704) zero xpad+sbpad; [704,960) weight casts/repacks;
//       [960,1984) spatial mean (2 rows per block).
__global__ __launch_bounds__(256) void prep_kernel(
    const float* __restrict__ x,
    const float* __restrict__ wq, const float* __restrict__ wk,
    const float* __restrict__ wv, const float* __restrict__ wa,
    const float* __restrict__ s1w, const float* __restrict__ s2w,
    const float* __restrict__ lw,
    u16* __restrict__ xpad, u16* __restrict__ sbpad,
    u16* __restrict__ wqh, u16* __restrict__ wkh,
    u16* __restrict__ wvb, u16* __restrict__ wab,
    u16* __restrict__ s1rep, u16* __restrict__ s2rep, u16* __restrict__ lwrep,
    float* __restrict__ mb) {
  const int blk = blockIdx.x;
  const int t = threadIdx.x;
  if (blk < 704) {
    const long CX = (long)8 * XPAD_ROWS * C / 8;
    const long CS = (long)8 * SPAD_ROWS * C / 8;
    u16x8 z = {0, 0, 0, 0, 0, 0, 0, 0};
    for (long k = (long)blk * 256 + t; k < CX + CS; k += 704L * 256) {
      if (k < CX) st8(xpad + k * 8, z);
      else st8(sbpad + (k - CX) * 8, z);
    }
  } else if (blk < 960) {
    int base = (blk - 704) * 256 + t;  // [0, 65536)
    wqh[base] = f2bf(wq[base]);
    wkh[base] = f2bf(wk[base]);
    wvb[base] = f2bf(wv[base]);
    wab[base] = f2bf(wa[base]);
    size_t b7 = (size_t)base * 7, b9 = (size_t)base * 9;
#pragma unroll
    for (int tp = 0; tp < 7; ++tp) s1rep[tp * 65536 + base] = f2bf(s1w[b7 + tp]);
#pragma unroll
    for (int tp = 0; tp < 7; ++tp) s2rep[tp * 65536 + base] = f2bf(s2w[b7 + tp]);
#pragma unroll
    for (int tp = 0; tp < 9; ++tp) lwrep[tp * 65536 + base] = f2bf(lw[b9 + tp]);
  } else {
    __shared__ float ws4[4];
    int r0 = (blk - 960) * 2;
#pragma unroll
    for (int rr = 0; rr < 2; ++rr) {
      const float* p = x + (size_t)(r0 + rr) * N;
      float s = 0.f;
      for (int i = t; i < N; i += 256) s += p[i];
#pragma unroll
      for (int off = 32; off >= 1; off >>= 1) s += __shfl_xor(s, off);
      if ((t & 63) == 0) ws4[t >> 6] = s;
      __syncthreads();
      if (t == 0) mb[r0 + rr] = (ws4[0] + ws4[1] + ws4[2] + ws4[3]) * (1.f / N);
      __syncthreads();
    }
  }
}

// ---------------------------------------------------------------------------
// x [B][C][N] fp32 -> xT bf16 [B][N][C]  +  xpad_hi [B][2916][C]
__global__ __launch_bounds__(256) void split_x_kernel(
    const float* __restrict__ x, u16* __restrict__ xhi,
    u16* __restrict__ xpad) {
  const int b = blockIdx.z;
  const int p0 = blockIdx.x * 64;
  const int c0 = blockIdx.y * 64;
  const int tid = threadIdx.x;
  __shared__ float tile[64][65];
#pragma unroll
  for (int it = 0; it < 4; ++it) {
    int idx = it * 256 + tid;
    int cr = idx >> 4, pc = (idx & 15) * 4;
    f4 v = *reinterpret_cast<const f4*>(&x[((size_t)b * C + c0 + cr) * N + p0 + pc]);
    tile[cr][pc] = v[0];
    tile[cr][pc + 1] = v[1];
    tile[cr][pc + 2] = v[2];
    tile[cr][pc + 3] = v[3];
  }
  __syncthreads();
#pragma unroll
  for (int it = 0; it < 2; ++it) {
    int idx = it * 256 + tid;
    int pr = idx >> 3, cg = (idx & 7) * 8;
    u16x8 h8;
#pragma unroll
    for (int j = 0; j < 8; ++j) h8[j] = f2bf(tile[cg + j][pr]);
    int p = p0 + pr;
    size_t o = ((size_t)b * N + p) * C + c0 + cg;
    st8(xhi + o, h8);
    int hh = p / HW, ww = p - hh * HW;
    size_t op = ((size_t)b * XPAD_ROWS + (size_t)(hh + 3) * 54 + ww + 3) * C + c0 + cg;
    st8(xpad + op, h8);
  }
}

__global__ __launch_bounds__(256) void global_kernel(
    const float* __restrict__ m, const float* __restrict__ g1w,
    const float* __restrict__ g1b, const float* __restrict__ g2w,
    const float* __restrict__ g2b, float* __restrict__ gatt) {
  int b = blockIdx.x, t = threadIdx.x;
  __shared__ float ms[256], hid[32];
  ms[t] = m[b * 256 + t];
  __syncthreads();
  if (t < 32) {
    float s = g1b[t];
    const float* wr = g1w + t * 256;
    for (int c2 = 0; c2 < 256; ++c2) s += ms[c2] * wr[c2];
    hid[t] = fmaxf(s, 0.f);
  }
  __syncthreads();
  float s = g2b[t];
#pragma unroll
  for (int j = 0; j < 32; ++j) s += hid[j] * g2w[t * 32 + j];
  gatt[b * 256 + t] = 1.f / (1.f + __expf(-s));
}

// ---------------------------------------------------------------------------
// Descriptor-driven fused GEMM (single-buffer m97 structure, (256,3)).
struct OpDesc {
  const u16* Xh;
  const u16* W;
  const float* bias;  // nullptr -> raw partial (no bias/act)
  u16* o0;
  int tk;      // 0 none, 1 = 1x7, 2 = 7x1, 3 = 3x3
  int act;     // 0 none, 1 relu, 2 sigmoid
  int outn;    // 0: out[pos][o], 1: out[o][pos]
  int opad;    // output to sb_pad geometry
  int ips;     // input rows per batch
  int idy;     // row delta for dy=+1
  int iox;     // column origin
  int s0, s1;  // step range over flattened (tap, ks)
};
struct OpPack {
  OpDesc d[6];
  int chunk;  // nwg/8 for XCD swizzle
  int ny;
};

__global__ __launch_bounds__(256, 3) void fused_gemm_kernel(OpPack pk) {
  const int swz = (blockIdx.x & 7) * pk.chunk + (blockIdx.x >> 3);
  const int xt = swz % 18;
  const int rest = swz / 18;
  const int y = rest % pk.ny;
  const int z = rest / pk.ny;
  const OpDesc dd = pk.d[y >> 1];
  const int mbase = xt * 128;
  const int nbase = (y & 1) * 128;
  const int tid = threadIdx.x;
  const int lane = tid & 63;
  const int wid = tid >> 6;
  const int wm = wid >> 1, wn = wid & 1;
  const int tk = dd.tk;

  __shared__ __align__(16) u16 ldsX[128 * 64];
  __shared__ __align__(16) u16 ldsW[128 * 64];

  f32x4 acc[4][4];
#pragma unroll
  for (int m = 0; m < 4; ++m)
#pragma unroll
    for (int n = 0; n < 4; ++n) acc[m][n] = f32x4{0.f, 0.f, 0.f, 0.f};

  size_t xrow[4], wrow[4];
#pragma unroll
  for (int it = 0; it < 4; ++it) {
    int idx = it * 256 + tid;
    int rr = idx >> 3, ss = idx & 7;
    int perm = ss ^ (rr & 7);
    int p = mbase + rr;
    if (tk == 0) {
      xrow[it] = ((size_t)z * N + p) * 512 + (size_t)perm * 16;
    } else {
      int hh = p / HW, ww = p - hh * HW;
      xrow[it] = ((size_t)z * dd.ips + (size_t)(hh + 3) * dd.idy + ww + dd.iox) * 512 +
                 (size_t)perm * 16;
    }
    wrow[it] = ((size_t)(nbase + rr)) * 512 + (size_t)perm * 16;
  }
  int aoff[2][4], boff[2][4];
#pragma unroll
  for (int kk = 0; kk < 2; ++kk) {
    int seg = kk * 4 + (lane >> 4);
#pragma unroll
    for (int m = 0; m < 4; ++m) {
      int ra = wm * 64 + m * 16 + (lane & 15);
      aoff[kk][m] = ra * 64 + ((seg ^ (ra & 7)) << 3);
      int rb = wn * 64 + m * 16 + (lane & 15);
      boff[kk][m] = rb * 64 + ((seg ^ (rb & 7)) << 3);
    }
  }

  auto stage = [&](int tap, int ks) {
    const char* xs = (const char*)dd.Xh;
    const char* wsrc = (const char*)dd.W + (size_t)tap * 131072;
    int tsh = 0;
    if (tk == 1) tsh = tap - 3;
    else if (tk == 2) tsh = (tap - 3) * dd.idy;
    else if (tk == 3) tsh = (tap / 3 - 1) * dd.idy + (tap % 3 - 1);
    const long xadd = (long)tsh * 512 + ks * 128;
    const long wadd = ks * 128;
#pragma unroll
    for (int it = 0; it < 4; ++it) {
      gl16(xs + xrow[it] + xadd, &ldsX[(it * 4 + wid) * 512]);
      gl16(wsrc + wrow[it] + wadd, &ldsW[(it * 4 + wid) * 512]);
    }
  };

  int t0 = dd.s0;
  int cks = t0 & 3;
  int ctap = t0 >> 2;
  stage(ctap, cks);

#pragma unroll 1
  for (int t = dd.s0; t < dd.s1; ++t) {
    __syncthreads();  // staging drained & visible
    const u16* Alds = dd.outn ? ldsW : ldsX;
    const u16* Blds = dd.outn ? ldsX : ldsW;
#pragma unroll
    for (int kk = 0; kk < 2; ++kk) {
      u16x8 af[4], bfr[4];
#pragma unroll
      for (int m = 0; m < 4; ++m) af[m] = ld8(&Alds[aoff[kk][m]]);
#pragma unroll
      for (int n = 0; n < 4; ++n) bfr[n] = ld8(&Blds[boff[kk][n]]);
      __builtin_amdgcn_s_setprio(1);
#pragma unroll
      for (int m = 0; m < 4; ++m)
#pragma unroll
        for (int n = 0; n < 4; ++n)
          acc[m][n] = mfma16(af[m], bfr[n], acc[m][n]);
      __builtin_amdgcn_s_setprio(0);
    }
    __syncthreads();  // all LDS reads done before next stage overwrites
    if (t + 1 < dd.s1) {
      if (++cks == 4) { cks = 0; ++ctap; }
      stage(ctap, cks);
    }
  }

  const int r4 = (lane >> 4) * 4, cl = lane & 15;
  const size_t xb = (size_t)z * BSTRIDE;
#pragma unroll
  for (int m = 0; m < 4; ++m) {
#pragma unroll
    for (int n = 0; n < 4; ++n) {
#pragma unroll
      for (int i = 0; i < 4; ++i) {
        int lrow = wm * 64 + m * 16 + r4 + i;
        int lcol = wn * 64 + n * 16 + cl;
        int o = dd.outn ? (nbase + lrow) : (nbase + lcol);
        int pos = dd.outn ? (mbase + lcol) : (mbase + lrow);
        float v = acc[m][n][i];
        if (dd.bias) {
          v += dd.bias[o];
          if (dd.act == 1) v = fmaxf(v, 0.f);
          else if (dd.act == 2) v = 1.f / (1.f + __expf(-v));
        }
        size_t oi;
        if (dd.opad) {
          int hh = pos / HW, ww = pos - hh * HW;
          oi = ((size_t)z * SPAD_ROWS + (size_t)(hh + 3) * 48 + ww) * C + o;
        } else {
          oi = xb + (dd.outn ? ((size_t)o * N + pos) : ((size_t)pos * C + o));
        }
        dd.o0[oi] = f2bf(v);
      }
    }
  }
}

// ---------------------------------------------------------------------------
// Flash attention, split-K=4 (round-13 structure). 1-term QK; K/V register
// prefetch; ones-MFMA row-sum; defer-max. (256,2) — non-spilling bound.
__global__ __launch_bounds__(256, 2) void flash_kernel(
    const u16* __restrict__ Qhi, const u16* __restrict__ Khi,
    const u16* __restrict__ Vb, u16* __restrict__ P0, u16* __restrict__ P1,
    u16* __restrict__ P2, u16* __restrict__ P3, float* __restrict__ ML) {
  const int b = blockIdx.y;
  const int split = blockIdx.z;
  const int q0 = blockIdx.x * 64;
  const int tid = threadIdx.x;
  const int lane = tid & 63;
  const int wid = tid >> 6;
  const int qbase = q0 + wid * 16;
  const int bb = b * N;
  const u16* Vp = Vb + (size_t)b * BSTRIDE;

  __shared__ __align__(16) u16 lds_kh[32 * 256];
  __shared__ __align__(16) u16 lds_v[256 * 32];
  __shared__ __align__(16) u16 p_lds[4][16 * 40];

  u16x8 qfh[8];
  {
    size_t base = ((size_t)(bb + qbase + (lane & 15))) * C + (lane >> 4) * 8;
#pragma unroll
    for (int kc = 0; kc < 8; ++kc) qfh[kc] = ld8(Qhi + base + kc * 32);
  }
  const u16x8 ones = {0x3F80, 0x3F80, 0x3F80, 0x3F80,
                      0x3F80, 0x3F80, 0x3F80, 0x3F80};  // bf16 1.0

  f32x4 o_acc[16];
#pragma unroll
  for (int j = 0; j < 16; ++j) o_acc[j] = f32x4{0.f, 0.f, 0.f, 0.f};
  float m_r[4] = {-1e30f, -1e30f, -1e30f, -1e30f};
  f32x4 l_acc = {0.f, 0.f, 0.f, 0.f};

  u16x8 skh[4], sv[4];
  const int kt0 = split * 18;
  auto issue = [&](int kt) {
    const int k0 = kt * 32;
#pragma unroll
    for (int it = 0; it < 4; ++it) {
      int idx = it * 256 + tid;
      int r = idx >> 5, s = idx & 31;
      skh[it] = ld8(Khi + (size_t)(bb + k0 + r) * C + s * 8);
      int c2 = idx >> 2, s2 = idx & 3;
      sv[it] = ld8(Vp + (size_t)c2 * N + k0 + s2 * 8);
    }
  };
  issue(kt0);

#pragma unroll 1
  for (int t2 = 0; t2 < 18; ++t2) {
    __syncthreads();
#pragma unroll
    for (int it = 0; it < 4; ++it) {
      int idx = it * 256 + tid;
      int r = idx >> 5, s = idx & 31;
      st8(&lds_kh[r * 256 + ((s ^ (r & 7)) << 3)], skh[it]);
      int c2 = idx >> 2, s2 = idx & 3;
      st8(&lds_v[c2 * 32 + ((s2 ^ ((c2 >> 1) & 3)) << 3)], sv[it]);
    }
    __syncthreads();
    if (t2 < 17) issue(kt0 + t2 + 1);

    // 1-term QK^T
    f32x4 sa0 = {0.f, 0.f, 0.f, 0.f}, sa1 = {0.f, 0.f, 0.f, 0.f};
    __builtin_amdgcn_s_setprio(1);
#pragma unroll
    for (int kc = 0; kc < 8; ++kc) {
      int seg = kc * 4 + (lane >> 4);
      int r0 = lane & 15, r1 = 16 + (lane & 15);
      u16x8 b0 = ld8(&lds_kh[r0 * 256 + ((seg ^ (r0 & 7)) << 3)]);
      u16x8 b1 = ld8(&lds_kh[r1 * 256 + ((seg ^ (r1 & 7)) << 3)]);
      sa0 = mfma16(qfh[kc], b0, sa0);
      sa1 = mfma16(qfh[kc], b1, sa1);
    }
    __builtin_amdgcn_s_setprio(0);

    // online softmax with defer-max (THR=8); row max via 4 shuffles
    float tm[4];
#pragma unroll
    for (int i = 0; i < 4; ++i) {
      float v = fmaxf(sa0[i], sa1[i]);
      v = fmaxf(v, __shfl_xor(v, 1));
      v = fmaxf(v, __shfl_xor(v, 2));
      v = fmaxf(v, __shfl_xor(v, 4));
      v = fmaxf(v, __shfl_xor(v, 8));
      tm[i] = v;
    }
    bool need = (tm[0] > m_r[0] + 8.f) | (tm[1] > m_r[1] + 8.f) |
                (tm[2] > m_r[2] + 8.f) | (tm[3] > m_r[3] + 8.f);
    if (__any(need)) {
      float sc[4];
#pragma unroll
      for (int i = 0; i < 4; ++i) {
        float mn = fmaxf(m_r[i], tm[i]);
        sc[i] = __expf(m_r[i] - mn);
        m_r[i] = mn;
        l_acc[i] *= sc[i];
      }
#pragma unroll
      for (int j = 0; j < 16; ++j) {
#pragma unroll
        for (int i = 0; i < 4; ++i) o_acc[j][i] *= sc[i];
      }
    }
    // P -> bf16 -> p_lds (l comes from ones-MFMA below)
    u16* pl = p_lds[wid];
#pragma unroll
    for (int i = 0; i < 4; ++i) {
      float p0 = __expf(sa0[i] - m_r[i]);
      float p1 = __expf(sa1[i] - m_r[i]);
      int row = (lane >> 4) * 4 + i;
      pl[row * 40 + (lane & 15)] = f2bf(p0);
      pl[row * 40 + 16 + (lane & 15)] = f2bf(p1);
    }
    u16x8 pa = ld8(&pl[(lane & 15) * 40 + (lane >> 4) * 8]);
    __builtin_amdgcn_s_setprio(1);
    l_acc = mfma16(pa, ones, l_acc);  // row sums of P
#pragma unroll
    for (int cf = 0; cf < 16; ++cf) {
      int col = cf * 16 + (lane & 15);
      u16x8 bv = ld8(&lds_v[col * 32 + (((lane >> 4) ^ ((col >> 1) & 3)) << 3)]);
      o_acc[cf] = mfma16(pa, bv, o_acc[cf]);
    }
    __builtin_amdgcn_s_setprio(0);
  }

  float rl[4];
#pragma unroll
  for (int i = 0; i < 4; ++i) rl[i] = 1.f / l_acc[i];
  u16* Pout = (split == 0) ? P0 : (split == 1) ? P1 : (split == 2) ? P2 : P3;
#pragma unroll
  for (int cf = 0; cf < 16; ++cf) {
#pragma unroll
    for (int i = 0; i < 4; ++i) {
      int q = qbase + (lane >> 4) * 4 + i;
      int c2 = cf * 16 + (lane & 15);
      Pout[(size_t)(bb + q) * C + c2] = f2bf(o_acc[cf][i] * rl[i]);
    }
  }
  if ((lane & 15) == 0) {
#pragma unroll
    for (int i = 0; i < 4; ++i) {
      int q = qbase + (lane >> 4) * 4 + i;
      ML[split * BN + bb + q] = m_r[i];
      ML[(4 + split) * BN + bb + q] = l_acc[i];
    }
  }
}

// ---------------------------------------------------------------------------
// out = x*(1+gatt+sigmoid(sp0+sp1+s2b)) + local + anchor + merge4(P0..P3;ML)
__global__ __launch_bounds__(256) void compose_kernel(
    const float* __restrict__ x, const float* __restrict__ gatt,
    const u16* __restrict__ sp0, const u16* __restrict__ sp1,
    const float* __restrict__ s2b, const u16* __restrict__ localT,
    const u16* __restrict__ anchT, const u16* __restrict__ P0,
    const u16* __restrict__ P1, const u16* __restrict__ P2,
    const u16* __restrict__ P3, const float* __restrict__ ML,
    float* __restrict__ out) {
  const int b = blockIdx.y;
  const int p0 = blockIdx.x * 32;
  const int t = threadIdx.x;
  const int bb = b * N;
  __shared__ __align__(16) u16 lsA[32 * 72], lsL[32 * 72], lsO[32 * 72];
  __shared__ float aw[4][32];
  if (t < 32) {
    int gq = bb + p0 + t;
    float m0 = ML[gq], m1 = ML[BN + gq], m2 = ML[2 * BN + gq],
          m3 = ML[3 * BN + gq];
    float M = fmaxf(fmaxf(m0, m1), fmaxf(m2, m3));
    float w0 = ML[4 * BN + gq] * __expf(m0 - M);
    float w1 = ML[5 * BN + gq] * __expf(m1 - M);
    float w2 = ML[6 * BN + gq] * __expf(m2 - M);
    float w3 = ML[7 * BN + gq] * __expf(m3 - M);
    float inv = 1.f / (w0 + w1 + w2 + w3);
    aw[0][t] = w0 * inv;
    aw[1][t] = w1 * inv;
    aw[2][t] = w2 * inv;
    aw[3][t] = w3 * inv;
  }
#pragma unroll 1
  for (int cc = 0; cc < 4; ++cc) {
    const int c0 = cc * 64;
    __syncthreads();
    {
      int r = t >> 3, s = t & 7;
      size_t g = (size_t)(bb + p0 + r) * C + c0 + s * 8;
      u16x8 q0 = ld8(sp0 + g), q1 = ld8(sp1 + g), sa8;
#pragma unroll
      for (int j = 0; j < 8; ++j) {
        float v = bf2f(q0[j]) + bf2f(q1[j]) + s2b[c0 + s * 8 + j];
        sa8[j] = f2bf(1.f / (1.f + __expf(-v)));
      }
      st8(&lsA[r * 72 + s * 8], sa8);
      st8(&lsL[r * 72 + s * 8], ld8(localT + g));
      u16x8 a0 = ld8(P0 + g), a1 = ld8(P1 + g), a2 = ld8(P2 + g),
            a3 = ld8(P3 + g), an = ld8(anchT + g);
      float w0 = aw[0][r], w1 = aw[1][r], w2 = aw[2][r], w3 = aw[3][r];
      u16x8 om;
#pragma unroll
      for (int j = 0; j < 8; ++j)
        om[j] = f2bf(w0 * bf2f(a0[j]) + w1 * bf2f(a1[j]) + w2 * bf2f(a2[j]) +
                     w3 * bf2f(a3[j]) + bf2f(an[j]));
      st8(&lsO[r * 72 + s * 8], om);
    }
    __syncthreads();
    int pl = t & 31, cg = t >> 5;
    int p = p0 + pl;
#pragma unroll
    for (int j = 0; j < 8; ++j) {
      int c2 = c0 + cg * 8 + j;
      size_t xi = ((size_t)b * C + c2) * N + p;
      float xv = x[xi];
      float sa = bf2f(lsA[pl * 72 + (c2 - c0)]);
      float lf = bf2f(lsL[pl * 72 + (c2 - c0)]);
      float om = bf2f(lsO[pl * 72 + (c2 - c0)]);
      float ga = gatt[b * 256 + c2];
      out[xi] = xv * (1.f + ga + sa) + lf + om;
    }
  }
}

// ---------------------------------------------------------------------------
extern "C" void kernel_launch(void* const* d_in, const int* in_sizes, int n_in,
                              void* d_out, int out_size, void* d_ws,
                              size_t ws_size, hipStream_t stream) {
  (void)in_sizes; (void)n_in; (void)out_size; (void)ws_size;
  const float* x   = (const float*)d_in[0];
  const float* wq  = (const float*)d_in[1];
  const float* bq  = (const float*)d_in[2];
  const float* wk  = (const float*)d_in[3];
  const float* bk  = (const float*)d_in[4];
  const float* wv  = (const float*)d_in[5];
  const float* bv  = (const float*)d_in[6];
  const float* wa  = (const float*)d_in[7];
  const float* ba  = (const float*)d_in[8];
  const float* g1w = (const float*)d_in[9];
  const float* g1b = (const float*)d_in[10];
  const float* g2w = (const float*)d_in[11];
  const float* g2b = (const float*)d_in[12];
  const float* s1w = (const float*)d_in[13];
  const float* s1b = (const float*)d_in[14];
  const float* s2w = (const float*)d_in[15];
  const float* s2b = (const float*)d_in[16];
  const float* lw  = (const float*)d_in[17];
  const float* lb  = (const float*)d_in[18];
  float* out = (float*)d_out;

  char* w = (char*)d_ws;
  const size_t SZB = (size_t)8 * N * C * sizeof(u16);          // 9,437,184 B
  const size_t SZXP = (size_t)8 * XPAD_ROWS * C * sizeof(u16); // 11,943,936 B
  const size_t SZSP = (size_t)8 * SPAD_ROWS * C * sizeof(u16); // 10,616,832 B
  u16* xhiT   = (u16*)(w + 0 * SZB);   // input xT
  u16* sp0    = (u16*)(w + 1 * SZB);   // s2 partial 0
  u16* sp1    = (u16*)(w + 2 * SZB);   // s2 partial 1
  u16* qhiT   = (u16*)(w + 3 * SZB);
  u16* khiT   = (u16*)(w + 4 * SZB);
  u16* vbuf   = (u16*)(w + 5 * SZB);
  u16* localT = (u16*)(w + 6 * SZB);
  u16* OTb    = (u16*)(w + 7 * SZB);   // anchor
  u16* Pf0    = (u16*)(w + 8 * SZB);   // flash partial 0
  u16* Pf1    = (u16*)(w + 9 * SZB);   // flash partial 1
  u16* xpad   = (u16*)(w + 10 * SZB);             // -> flash partial 2
  u16* sbpad  = (u16*)(w + 10 * SZB + SZXP);      // -> flash partial 3
  char* wp = w + 10 * SZB + SZXP + SZSP;
  u16* wqh   = (u16*)(wp + 0);
  u16* wkh   = (u16*)(wp + 131072);
  u16* wvb   = (u16*)(wp + 262144);
  u16* wab   = (u16*)(wp + 393216);
  u16* s1rep = (u16*)(wp + 524288);
  u16* s2rep = (u16*)(wp + 1441792);
  u16* lwrep = (u16*)(wp + 2359296);
  float* mb    = (float*)(wp + 3538944);
  float* gattb = (float*)(wp + 3547136);
  float* ML    = (float*)(wp + 3555328);  // 8*BN floats

  // 1: prep (zero pads + weights + mean)
  prep_kernel<<<1984, 256, 0, stream>>>(x, wq, wk, wv, wa, s1w, s2w, lw,
                                        xpad, sbpad, wqh, wkh, wvb, wab,
                                        s1rep, s2rep, lwrep, mb);
  // 2: transpose + bf16 cast (+ padded copy)
  split_x_kernel<<<dim3(36, 4, 8), 256, 0, stream>>>(x, xhiT, xpad);
  // 3: squeeze-excite gate
  global_kernel<<<8, 256, 0, stream>>>(mb, g1w, g1b, g2w, g2b, gattb);

  // 4: one fused dispatch: local(3x3), s1(1x7), q, k, v, anchor
  OpPack pk;
  pk.d[0] = {xpad, lwrep, lb, localT, 3, 1, 0, 0, XPAD_ROWS, 54, 3, 0, 36};
  pk.d[1] = {xpad, s1rep, s1b, sbpad,  1, 1, 0, 1, XPAD_ROWS, 54, 3, 0, 28};
  pk.d[2] = {xhiT, wqh,   bq, qhiT,    0, 0, 0, 0, N, 0, 0, 0, 4};
  pk.d[3] = {xhiT, wkh,   bk, khiT,    0, 0, 0, 0, N, 0, 0, 0, 4};
  pk.d[4] = {xhiT, wvb,   bv, vbuf,    0, 0, 1, 0, N, 0, 0, 0, 4};
  pk.d[5] = {xhiT, wab,   ba, OTb,     0, 0, 0, 0, N, 0, 0, 0, 4};
  pk.chunk = 1728 / 8;
  pk.ny = 12;
  fused_gemm_kernel<<<dim3(1728), 256, 0, stream>>>(pk);

  // 5: spectral second conv, split-K=2 raw partials -> sp0/sp1
  OpPack pk2;
  pk2.d[0] = {sbpad, s2rep, nullptr, sp0, 2, 0, 0, 0, SPAD_ROWS, 48, 0, 0, 14};
  pk2.d[1] = {sbpad, s2rep, nullptr, sp1, 2, 0, 0, 0, SPAD_ROWS, 48, 0, 14, 28};
  pk2.chunk = 576 / 8;
  pk2.ny = 4;
  fused_gemm_kernel<<<dim3(576), 256, 0, stream>>>(pk2);

  // 6: flash attention, split-K=4 (partials into dead buffers)
  flash_kernel<<<dim3(36, 8, 4), 256, 0, stream>>>(
      qhiT, khiT, vbuf, Pf0, Pf1, xpad, sbpad, ML);

  // 7: final composition (s2 finish + split-K merge + anchor)
  compose_kernel<<<dim3(72, 8), 256, 0, stream>>>(
      x, gattb, sp0, sp1, s2b, localT, OTb, Pf0, Pf1, xpad, sbpad, ML, out);
}